// Round 1
// baseline (986.900 us; speedup 1.0000x reference)
//
#include <hip/hip_runtime.h>
#include <hip/hip_bf16.h>
#include <math.h>
#include <stdint.h>
#include <stddef.h>

// ---------------------------------------------------------------------------
// MetaEvidentialGSL: N=8192, D=768, H1=512, H2=256
// Pipeline:
//  1. split X into bf16 hi/lo; transpose+convert weights to bf16 (split for heads)
//  2. head1 via split-bf16 MFMA GEMMs -> m0,v0,a0,b0 (fp32) + gate G
//  3. QKV = X @ [Wq|Wk|Wg] (one bf16 GEMM, N=2304); V transposed for reuse
//  4. attention in 8 column panels: Wp = exp(QK^T/sqrt(D))*G_j (bf16) with
//     row-sum atomics E (plain exp) and T (exp*G); Macc += Wp @ V  (fp32)
//  5. fuse: Y = X + gelu(alpha*Macc + bg), alpha = G/(E*max(G*T/E,1e-8))
//     (exactly reproduces reference clamp semantics incl. G==0 rows)
//  6. head2 on Y (split-bf16) -> mu,v,al,be
// ---------------------------------------------------------------------------

#define NT    8192
#define DD    768
#define DH1   512
#define DH2   256
#define PANEL 1024
#define NPAN  (NT / PANEL)

typedef __attribute__((ext_vector_type(8))) short  short8;
typedef __attribute__((ext_vector_type(4))) float  f32x4;

#define MFMA16(a, b, c) __builtin_amdgcn_mfma_f32_16x16x32_bf16((a), (b), (c), 0, 0, 0)

__device__ __forceinline__ float bf2f(__hip_bfloat16 x) { return __bfloat162float(x); }
__device__ __forceinline__ __hip_bfloat16 f2bf(float x) { return __float2bfloat16(x); }

__device__ __forceinline__ float gelu_f(float x) {
    return 0.5f * x * (1.0f + erff(x * 0.7071067811865476f));
}
// accuracy-critical (feeds G-cliff): use exact expf
__device__ __forceinline__ float softplus_f(float x) {
    return (x > 20.0f) ? x : log1pf(expf(x));
}

// async 16B/lane global->LDS. LDS dest must be wave-uniform base + lane*16.
__device__ __forceinline__ void gload16(const __hip_bfloat16* g, __hip_bfloat16* l) {
    __builtin_amdgcn_global_load_lds(
        (const __attribute__((address_space(1))) void*)(const void*)g,
        (__attribute__((address_space(3))) void*)(void*)l,
        16, 0, 0);
}

// ---------------------------------------------------------------------------
// GEMM: C(MxN) = A(MxK) @ Bt(NxK)^T, 128x128 tile, BK=32, 4 waves (2x2 of 64x64)
// SPLIT: A,B given as hi+lo bf16 pairs; computes hi*hi + hi*lo + lo*hi.
// EPI: 0 = store bf16; 1 = bias+gelu -> split bf16 (hi/lo)
//      2 = w=exp(acc/sqrt(D))*G[col] -> bf16, atomic rowsum E (exp) / T (w)
//      3 = fp32 accumulate (ofp[idx] += acc)
// ---------------------------------------------------------------------------
template <int EPI, bool SPLIT>
__global__ __launch_bounds__(256)
void gemm_bt(const __hip_bfloat16* __restrict__ Ahi, const __hip_bfloat16* __restrict__ Alo, int lda,
             const __hip_bfloat16* __restrict__ Bhi, const __hip_bfloat16* __restrict__ Blo, int ldb,
             __hip_bfloat16* __restrict__ obf_hi, __hip_bfloat16* __restrict__ obf_lo,
             float* __restrict__ ofp, int ldc,
             const float* __restrict__ bias, const float* __restrict__ Gv,
             float* __restrict__ Esum, float* __restrict__ Tsum, int K)
{
    constexpr int NB = SPLIT ? 2 : 1;
    __shared__ __align__(16) __hip_bfloat16 As[NB][128 * 32];
    __shared__ __align__(16) __hip_bfloat16 Bs[NB][128 * 32];

    const int tid  = threadIdx.x;
    const int wave = tid >> 6;
    const int lane = tid & 63;
    const int tm = blockIdx.y * 128;
    const int tn = blockIdx.x * 128;

    // staging: each wave covers 16 rows/pass (4 lanes x 16B per 64B row), 2 passes
    const int srow = wave * 16 + (lane >> 2);
    const int scol = (lane & 3) * 8;
    const size_t aoff0 = (size_t)(tm + srow) * lda + scol;
    const size_t aoff1 = (size_t)(tm + 64 + srow) * lda + scol;
    const size_t boff0 = (size_t)(tn + srow) * ldb + scol;
    const size_t boff1 = (size_t)(tn + 64 + srow) * ldb + scol;
    const int lidx = srow * 32 + scol;   // == wave*512 + lane*8 elems (lane*16 B)

    f32x4 acc[4][4];
#pragma unroll
    for (int i = 0; i < 4; ++i)
#pragma unroll
        for (int j = 0; j < 4; ++j) {
            f32x4 z = {0.0f, 0.0f, 0.0f, 0.0f};
            acc[i][j] = z;
        }

    const int wm  = (wave >> 1) * 64;
    const int wn  = (wave & 1) * 64;
    const int l16 = lane & 15;
    const int quad = lane >> 4;

    for (int k0 = 0; k0 < K; k0 += 32) {
        gload16(Ahi + aoff0 + k0, &As[0][lidx]);
        gload16(Ahi + aoff1 + k0, &As[0][lidx + 64 * 32]);
        gload16(Bhi + boff0 + k0, &Bs[0][lidx]);
        gload16(Bhi + boff1 + k0, &Bs[0][lidx + 64 * 32]);
        if constexpr (SPLIT) {
            gload16(Alo + aoff0 + k0, &As[1][lidx]);
            gload16(Alo + aoff1 + k0, &As[1][lidx + 64 * 32]);
            gload16(Blo + boff0 + k0, &Bs[1][lidx]);
            gload16(Blo + boff1 + k0, &Bs[1][lidx + 64 * 32]);
        }
        __syncthreads();   // drains vmcnt -> LDS valid

        short8 ah[4], bh[4];
#pragma unroll
        for (int i = 0; i < 4; ++i) {
            ah[i] = *(const short8*)&As[0][(wm + i * 16 + l16) * 32 + quad * 8];
            bh[i] = *(const short8*)&Bs[0][(wn + i * 16 + l16) * 32 + quad * 8];
        }
        if constexpr (SPLIT) {
            short8 al[4], bl[4];
#pragma unroll
            for (int i = 0; i < 4; ++i) {
                al[i] = *(const short8*)&As[1][(wm + i * 16 + l16) * 32 + quad * 8];
                bl[i] = *(const short8*)&Bs[1][(wn + i * 16 + l16) * 32 + quad * 8];
            }
#pragma unroll
            for (int mi = 0; mi < 4; ++mi)
#pragma unroll
                for (int ni = 0; ni < 4; ++ni) {
                    acc[mi][ni] = MFMA16(ah[mi], bh[ni], acc[mi][ni]);
                    acc[mi][ni] = MFMA16(ah[mi], bl[ni], acc[mi][ni]);
                    acc[mi][ni] = MFMA16(al[mi], bh[ni], acc[mi][ni]);
                }
        } else {
#pragma unroll
            for (int mi = 0; mi < 4; ++mi)
#pragma unroll
                for (int ni = 0; ni < 4; ++ni)
                    acc[mi][ni] = MFMA16(ah[mi], bh[ni], acc[mi][ni]);
        }
        __syncthreads();   // before next-iter staging overwrites LDS
    }

    // C/D layout: col = lane&15, row = (lane>>4)*4 + reg  [verified m89/m91]
    const int rbase = tm + wm + quad * 4;
    const int cbase = tn + wn + l16;

    if constexpr (EPI == 0) {
#pragma unroll
        for (int mi = 0; mi < 4; ++mi)
#pragma unroll
            for (int ni = 0; ni < 4; ++ni) {
                f32x4 v = acc[mi][ni];
                const int col = cbase + ni * 16;
#pragma unroll
                for (int r = 0; r < 4; ++r)
                    obf_hi[(size_t)(rbase + mi * 16 + r) * ldc + col] = f2bf(v[r]);
            }
    } else if constexpr (EPI == 1) {
#pragma unroll
        for (int mi = 0; mi < 4; ++mi)
#pragma unroll
            for (int ni = 0; ni < 4; ++ni) {
                f32x4 v = acc[mi][ni];
                const int col = cbase + ni * 16;
                const float b = bias[col];
#pragma unroll
                for (int r = 0; r < 4; ++r) {
                    float g = gelu_f(v[r] + b);
                    __hip_bfloat16 h = f2bf(g);
                    size_t idx = (size_t)(rbase + mi * 16 + r) * ldc + col;
                    obf_hi[idx] = h;
                    obf_lo[idx] = f2bf(g - bf2f(h));
                }
            }
    } else if constexpr (EPI == 2) {
        const float SCL = 0.03608439182435161f;   // 1/sqrt(768)
#pragma unroll
        for (int mi = 0; mi < 4; ++mi) {
            float sE[4] = {0.f, 0.f, 0.f, 0.f};
            float sT[4] = {0.f, 0.f, 0.f, 0.f};
#pragma unroll
            for (int ni = 0; ni < 4; ++ni) {
                f32x4 v = acc[mi][ni];
                const int col = cbase + ni * 16;
                const float g = Gv[col];
#pragma unroll
                for (int r = 0; r < 4; ++r) {
                    float we = __expf(v[r] * SCL);
                    float w  = we * g;
                    obf_hi[(size_t)(rbase + mi * 16 + r) * ldc + col] = f2bf(w);
                    sE[r] += we;
                    sT[r] += w;
                }
            }
#pragma unroll
            for (int st = 1; st < 16; st <<= 1)
#pragma unroll
                for (int r = 0; r < 4; ++r) {
                    sE[r] += __shfl_xor(sE[r], st);
                    sT[r] += __shfl_xor(sT[r], st);
                }
            if (l16 == 0) {
#pragma unroll
                for (int r = 0; r < 4; ++r) {
                    atomicAdd(&Esum[rbase + mi * 16 + r], sE[r]);
                    atomicAdd(&Tsum[rbase + mi * 16 + r], sT[r]);
                }
            }
        }
    } else {  // EPI == 3: fp32 accumulate
#pragma unroll
        for (int mi = 0; mi < 4; ++mi)
#pragma unroll
            for (int ni = 0; ni < 4; ++ni) {
                f32x4 v = acc[mi][ni];
                const int col = cbase + ni * 16;
#pragma unroll
                for (int r = 0; r < 4; ++r) {
                    size_t idx = (size_t)(rbase + mi * 16 + r) * ldc + col;
                    ofp[idx] += v[r];
                }
            }
    }
}

// ---------------------------------------------------------------------------
// transpose f32 (RxC) -> bf16 (CxR), optional lo residual output
// grid(C/32, R/32), block 256
// ---------------------------------------------------------------------------
__global__ __launch_bounds__(256)
void transpose_f2b(const float* __restrict__ in, int ldin,
                   __hip_bfloat16* __restrict__ ohi, __hip_bfloat16* __restrict__ olo, int ldout)
{
    __shared__ float t[32][33];
    const int tx = threadIdx.x & 31;
    const int ty = threadIdx.x >> 5;
    const int r0 = blockIdx.y * 32;
    const int c0 = blockIdx.x * 32;
#pragma unroll
    for (int j = 0; j < 32; j += 8)
        t[ty + j][tx] = in[(size_t)(r0 + ty + j) * ldin + c0 + tx];
    __syncthreads();
#pragma unroll
    for (int j = 0; j < 32; j += 8) {
        float x = t[tx][ty + j];
        __hip_bfloat16 h = f2bf(x);
        size_t o = (size_t)(c0 + ty + j) * ldout + r0 + tx;
        ohi[o] = h;
        if (olo) olo[o] = f2bf(x - bf2f(h));
    }
}

__global__ __launch_bounds__(256)
void transpose_b2b(const __hip_bfloat16* __restrict__ in, int ldin,
                   __hip_bfloat16* __restrict__ out, int ldout)
{
    __shared__ __hip_bfloat16 t[32][33];
    const int tx = threadIdx.x & 31;
    const int ty = threadIdx.x >> 5;
    const int r0 = blockIdx.y * 32;
    const int c0 = blockIdx.x * 32;
#pragma unroll
    for (int j = 0; j < 32; j += 8)
        t[ty + j][tx] = in[(size_t)(r0 + ty + j) * ldin + c0 + tx];
    __syncthreads();
#pragma unroll
    for (int j = 0; j < 32; j += 8)
        out[(size_t)(c0 + ty + j) * ldout + r0 + tx] = t[tx][ty + j];
}

// X (f32) -> hi/lo bf16 split, 4 elems/thread
__global__ __launch_bounds__(256)
void cvt_split(const float* __restrict__ in, __hip_bfloat16* __restrict__ hi,
               __hip_bfloat16* __restrict__ lo)
{
    const int i = (blockIdx.x * 256 + threadIdx.x) * 4;
    f32x4 v = *(const f32x4*)(in + i);
#pragma unroll
    for (int k = 0; k < 4; ++k) {
        __hip_bfloat16 h = f2bf(v[k]);
        hi[i + k] = h;
        lo[i + k] = f2bf(v[k] - bf2f(h));
    }
}

// ---------------------------------------------------------------------------
// head tail: r = H2 @ Wh + bh (fp32, hi+lo input), NIG transforms, optional G.
// Replicates reference fp32 rounding order for a0 and (a0 - 1).
// grid(NT/64), block 256: 4 threads/row (one per output column c)
// ---------------------------------------------------------------------------
__global__ __launch_bounds__(256)
void head_tail(const __hip_bfloat16* __restrict__ H2hi, const __hip_bfloat16* __restrict__ H2lo,
               const float* __restrict__ Wh, const float* __restrict__ bh,
               const float* __restrict__ gamp,
               float* __restrict__ outBase, float* __restrict__ Gout)
{
    __shared__ float sa[64], sb[64];
    const int tid = threadIdx.x;
    const int rl  = tid >> 2;
    const int c   = tid & 3;
    const int row = blockIdx.x * 64 + rl;
    const __hip_bfloat16* hh = H2hi + (size_t)row * DH2;
    const __hip_bfloat16* hl = H2lo + (size_t)row * DH2;
    float acc = bh[c];
    for (int k = 0; k < DH2; ++k) {
        float h = bf2f(hh[k]) + bf2f(hl[k]);
        acc = fmaf(h, Wh[k * 4 + c], acc);
    }
    float sp = softplus_f(acc);
    if (c == 0) {
        outBase[row] = acc;                        // mu
    } else if (c == 1) {
        outBase[NT + row] = sp + 1e-6f;            // v
    } else if (c == 2) {
        float a0 = (sp + 1.0f) + 1e-6f;            // match ref assoc order
        outBase[2 * NT + row] = a0;
        if (Gout) sa[rl] = a0 - 1.0f;              // match ref's a0-1 rounding
    } else {
        float b0 = sp + 1e-6f;
        outBase[3 * NT + row] = b0;
        if (Gout) sb[rl] = b0;
    }
    if (Gout != nullptr) {
        __syncthreads();
        if (c == 0) {
            float u   = sb[rl] / fmaxf(sa[rl], 1e-8f);
            float sig = 1.0f / (1.0f + expf(-u));  // fp32 cliff identical to ref
            Gout[row] = 1.0f - gamp[0] * sig;
        }
    }
}

// ---------------------------------------------------------------------------
// Y = X + gelu(alpha*Macc + bg); alpha = G/(E*max(G*T/E,1e-8))  (exact clamp
// semantics; G==0 rows -> alpha=0 -> M=gelu(bg) as in reference). Split out.
// ---------------------------------------------------------------------------
__global__ __launch_bounds__(256)
void fuse_y(const float* __restrict__ X, const float* __restrict__ Macc,
            const float* __restrict__ G, const float* __restrict__ E,
            const float* __restrict__ T, const float* __restrict__ bg,
            __hip_bfloat16* __restrict__ Yhi, __hip_bfloat16* __restrict__ Ylo)
{
    const int i   = blockIdx.x * 256 + threadIdx.x;
    const int row = i / DD;
    const int col = i - row * DD;
    const float g = G[row], e = E[row], t = T[row];
    const float denom = fmaxf(g * t / e, 1e-8f);
    const float alpha = g / (e * denom);
    const float m = alpha * Macc[i];
    const float y = X[i] + gelu_f(m + bg[col]);
    __hip_bfloat16 h = f2bf(y);
    Yhi[i] = h;
    Ylo[i] = f2bf(y - bf2f(h));
}

// ---------------------------------------------------------------------------
extern "C" void kernel_launch(void* const* d_in, const int* in_sizes, int n_in,
                              void* d_out, int out_size, void* d_ws, size_t ws_size,
                              hipStream_t stream)
{
    (void)in_sizes; (void)n_in; (void)out_size; (void)ws_size;
    const float* X   = (const float*)d_in[0];
    const float* Wq  = (const float*)d_in[1];
    const float* Wk  = (const float*)d_in[2];
    const float* Wg  = (const float*)d_in[3];
    const float* bg  = (const float*)d_in[4];
    const float* gam = (const float*)d_in[5];
    const float* iW1 = (const float*)d_in[6];
    const float* ib1 = (const float*)d_in[7];
    const float* iW2 = (const float*)d_in[8];
    const float* ib2 = (const float*)d_in[9];
    const float* iWh = (const float*)d_in[10];
    const float* ibh = (const float*)d_in[11];
    const float* fW1 = (const float*)d_in[12];
    const float* fb1 = (const float*)d_in[13];
    const float* fW2 = (const float*)d_in[14];
    const float* fb2 = (const float*)d_in[15];
    const float* fWh = (const float*)d_in[16];
    const float* fbh = (const float*)d_in[17];
    float* out = (float*)d_out;

    char* cur = (char*)d_ws;
    auto alloc = [&](size_t bytes) -> char* {
        char* p = cur;
        cur += (bytes + 255) & ~(size_t)255;
        return p;
    };
    typedef __hip_bfloat16 bf;
    bf* Xhi    = (bf*)alloc((size_t)NT * DD * 2);
    bf* Xlo    = (bf*)alloc((size_t)NT * DD * 2);
    bf* WqkvT  = (bf*)alloc((size_t)3 * DD * DD * 2);    // [Wq^T; Wk^T; Wg^T] (2304 x 768)
    bf* iW1hiT = (bf*)alloc((size_t)DH1 * DD * 2);
    bf* iW1loT = (bf*)alloc((size_t)DH1 * DD * 2);
    bf* iW2hiT = (bf*)alloc((size_t)DH2 * DH1 * 2);
    bf* iW2loT = (bf*)alloc((size_t)DH2 * DH1 * 2);
    bf* fW1hiT = (bf*)alloc((size_t)DH1 * DD * 2);
    bf* fW1loT = (bf*)alloc((size_t)DH1 * DD * 2);
    bf* fW2hiT = (bf*)alloc((size_t)DH2 * DH1 * 2);
    bf* fW2loT = (bf*)alloc((size_t)DH2 * DH1 * 2);
    bf* QKV    = (bf*)alloc((size_t)NT * 3 * DD * 2);    // 8192 x 2304 (Q|K|V)
    bf* VbT    = (bf*)alloc((size_t)DD * NT * 2);        // 768 x 8192
    bf* H1hi   = (bf*)alloc((size_t)NT * DH1 * 2);
    bf* H1lo   = (bf*)alloc((size_t)NT * DH1 * 2);
    bf* H2hi   = (bf*)alloc((size_t)NT * DH2 * 2);
    bf* H2lo   = (bf*)alloc((size_t)NT * DH2 * 2);
    float* G    = (float*)alloc((size_t)NT * 4);
    float* E    = (float*)alloc((size_t)NT * 4);
    float* T    = (float*)alloc((size_t)NT * 4);
    bf* Wp     = (bf*)alloc((size_t)NT * PANEL * 2);     // 8192 x 1024 panel
    float* Macc = (float*)alloc((size_t)NT * DD * 4);
    bf* Yhi    = (bf*)alloc((size_t)NT * DD * 2);
    bf* Ylo    = (bf*)alloc((size_t)NT * DD * 2);

    const dim3 blk(256);

    // 1. converts / transposes
    cvt_split<<<dim3(NT * DD / 1024), blk, 0, stream>>>(X, Xhi, Xlo);
    transpose_f2b<<<dim3(DD / 32, DD / 32), blk, 0, stream>>>(Wq, DD, WqkvT, nullptr, DD);
    transpose_f2b<<<dim3(DD / 32, DD / 32), blk, 0, stream>>>(Wk, DD, WqkvT + (size_t)DD * DD, nullptr, DD);
    transpose_f2b<<<dim3(DD / 32, DD / 32), blk, 0, stream>>>(Wg, DD, WqkvT + (size_t)2 * DD * DD, nullptr, DD);
    transpose_f2b<<<dim3(DH1 / 32, DD / 32), blk, 0, stream>>>(iW1, DH1, iW1hiT, iW1loT, DD);
    transpose_f2b<<<dim3(DH2 / 32, DH1 / 32), blk, 0, stream>>>(iW2, DH2, iW2hiT, iW2loT, DH1);
    transpose_f2b<<<dim3(DH1 / 32, DD / 32), blk, 0, stream>>>(fW1, DH1, fW1hiT, fW1loT, DD);
    transpose_f2b<<<dim3(DH2 / 32, DH1 / 32), blk, 0, stream>>>(fW2, DH2, fW2hiT, fW2loT, DH1);

    // 2. head 1 (split-bf16 for G-cliff safety)
    gemm_bt<1, true><<<dim3(DH1 / 128, NT / 128), blk, 0, stream>>>(
        Xhi, Xlo, DD, iW1hiT, iW1loT, DD, H1hi, H1lo, nullptr, DH1, ib1, nullptr, nullptr, nullptr, DD);
    gemm_bt<1, true><<<dim3(DH2 / 128, NT / 128), blk, 0, stream>>>(
        H1hi, H1lo, DH1, iW2hiT, iW2loT, DH1, H2hi, H2lo, nullptr, DH2, ib2, nullptr, nullptr, nullptr, DH1);
    head_tail<<<dim3(NT / 64), blk, 0, stream>>>(H2hi, H2lo, iWh, ibh, gam, out, G);

    // 3. QKV projection (single GEMM, N=2304)
    gemm_bt<0, false><<<dim3(3 * DD / 128, NT / 128), blk, 0, stream>>>(
        Xhi, nullptr, DD, WqkvT, nullptr, DD, QKV, nullptr, nullptr, 3 * DD,
        nullptr, nullptr, nullptr, nullptr, DD);
    transpose_b2b<<<dim3(DD / 32, NT / 32), blk, 0, stream>>>(QKV + 2 * DD, 3 * DD, VbT, NT);

    hipMemsetAsync(E, 0, (size_t)NT * 4, stream);
    hipMemsetAsync(T, 0, (size_t)NT * 4, stream);
    hipMemsetAsync(Macc, 0, (size_t)NT * DD * 4, stream);

    // 4. attention panels
    for (int p = 0; p < NPAN; ++p) {
        const bf* Kp = QKV + (size_t)p * PANEL * (3 * DD) + DD;   // K rows j0.., col offset 768
        gemm_bt<2, false><<<dim3(PANEL / 128, NT / 128), blk, 0, stream>>>(
            QKV, nullptr, 3 * DD, Kp, nullptr, 3 * DD, Wp, nullptr, nullptr, PANEL,
            nullptr, G + p * PANEL, E, T, DD);
        gemm_bt<3, false><<<dim3(DD / 128, NT / 128), blk, 0, stream>>>(
            Wp, nullptr, PANEL, VbT + p * PANEL, nullptr, NT, nullptr, nullptr, Macc, DD,
            nullptr, nullptr, nullptr, nullptr, PANEL);
    }

    // 5. Y = X + gelu(alpha*Macc + bg)
    fuse_y<<<dim3(NT * DD / 256), blk, 0, stream>>>(X, Macc, G, E, T, bg, Yhi, Ylo);

    // 6. head 2
    gemm_bt<1, true><<<dim3(DH1 / 128, NT / 128), blk, 0, stream>>>(
        Yhi, Ylo, DD, fW1hiT, fW1loT, DD, H1hi, H1lo, nullptr, DH1, fb1, nullptr, nullptr, nullptr, DD);
    gemm_bt<1, true><<<dim3(DH2 / 128, NT / 128), blk, 0, stream>>>(
        H1hi, H1lo, DH1, fW2hiT, fW2loT, DH1, H2hi, H2lo, nullptr, DH2, fb2, nullptr, nullptr, nullptr, DH1);
    head_tail<<<dim3(NT / 64), blk, 0, stream>>>(H2hi, H2lo, fWh, fbh, gam, out + 4 * NT, nullptr);
}

// Round 2
// 789.533 us; speedup vs baseline: 1.2500x; 1.2500x over previous
//
#include <hip/hip_runtime.h>
#include <hip/hip_bf16.h>
#include <math.h>
#include <stdint.h>
#include <stddef.h>

// ---------------------------------------------------------------------------
// MetaEvidentialGSL: N=8192, D=768, H1=512, H2=256
//  1. split X into bf16 hi/lo; transpose+convert weights to bf16
//  2. head1 via split-bf16 MFMA GEMMs -> m0,v0,a0,b0 + gate G
//  3. QKV = X @ [Wq|Wk|Wg] (one bf16 GEMM); V transposed
//  4. attention in 4 panels of 2048: Wp = exp(QK^T/sqrt(D))*G_j (bf16) with
//     row-sum atomics E/T; Macc += Wp @ V (fp32)
//  5. Y = X + gelu(alpha*Macc + bg), alpha = G/(E*max(G*T/E,1e-8))
//  6. head2 on Y -> mu,v,al,be
// R1: grid-size fixes (PANEL=2048; 128x64 / 64x64 tile variants) + LDS XOR
//     chunk swizzle (kills the 4-way ds_read_b128 bank conflicts).
// ---------------------------------------------------------------------------

#define NT    8192
#define DD    768
#define DH1   512
#define DH2   256
#define PANEL 2048
#define NPAN  (NT / PANEL)

typedef __attribute__((ext_vector_type(8))) short  short8;
typedef __attribute__((ext_vector_type(4))) float  f32x4;

#define MFMA16(a, b, c) __builtin_amdgcn_mfma_f32_16x16x32_bf16((a), (b), (c), 0, 0, 0)

__device__ __forceinline__ float bf2f(__hip_bfloat16 x) { return __bfloat162float(x); }
__device__ __forceinline__ __hip_bfloat16 f2bf(float x) { return __float2bfloat16(x); }

__device__ __forceinline__ float gelu_f(float x) {
    return 0.5f * x * (1.0f + erff(x * 0.7071067811865476f));
}
__device__ __forceinline__ float softplus_f(float x) {
    return (x > 20.0f) ? x : log1pf(expf(x));
}

// async 16B/lane global->LDS. LDS dest must be wave-uniform base + lane*16.
__device__ __forceinline__ void gload16(const __hip_bfloat16* g, __hip_bfloat16* l) {
    __builtin_amdgcn_global_load_lds(
        (const __attribute__((address_space(1))) void*)(const void*)g,
        (__attribute__((address_space(3))) void*)(void*)l,
        16, 0, 0);
}

// ---------------------------------------------------------------------------
// GEMM: C(MxN) = A(MxK) @ Bt(NxK)^T. Tile TM x TN, BK=32, 4 waves, 256 thr.
// LDS layout: row-major 32-elem rows, 16B chunk c of row r stored at slot
// c ^ ((r>>1)&3)  -> each 8-lane group of a ds_read_b128 covers all 8
// bank-groups (conflict-free); staging applies the same XOR to the global
// source column so the global_load_lds dest stays base + lane*16.
// SPLIT: A,B given as hi+lo bf16 pairs; computes hi*hi + hi*lo + lo*hi.
// EPI: 0 = store bf16; 1 = bias+gelu -> split bf16 (hi/lo)
//      2 = w=exp(acc/sqrt(D))*G[col] -> bf16, atomic rowsum E (exp) / T (w)
//      3 = fp32 accumulate (ofp[idx] += acc)
// ---------------------------------------------------------------------------
template <int EPI, bool SPLIT, int TM, int TN>
__global__ __launch_bounds__(256)
void gemm_bt(const __hip_bfloat16* __restrict__ Ahi, const __hip_bfloat16* __restrict__ Alo, int lda,
             const __hip_bfloat16* __restrict__ Bhi, const __hip_bfloat16* __restrict__ Blo, int ldb,
             __hip_bfloat16* __restrict__ obf_hi, __hip_bfloat16* __restrict__ obf_lo,
             float* __restrict__ ofp, int ldc,
             const float* __restrict__ bias, const float* __restrict__ Gv,
             float* __restrict__ Esum, float* __restrict__ Tsum, int K)
{
    constexpr int NB  = SPLIT ? 2 : 1;
    constexpr int WRM = (TM == 128 && TN == 128) ? 2 : (TM == 128 ? 4 : 2);
    constexpr int WCN = 4 / WRM;
    constexpr int WTM = TM / WRM;   // wave tile M
    constexpr int WTN = TN / WCN;   // wave tile N
    constexpr int MI  = WTM / 16;
    constexpr int NI  = WTN / 16;
    constexpr int PA  = TM / 64;    // staging passes for A
    constexpr int PB  = TN / 64;

    __shared__ __align__(16) __hip_bfloat16 As[NB][TM * 32];
    __shared__ __align__(16) __hip_bfloat16 Bs[NB][TN * 32];

    const int tid  = threadIdx.x;
    const int wave = tid >> 6;
    const int lane = tid & 63;
    const int tm = blockIdx.y * TM;
    const int tn = blockIdx.x * TN;

    // staging: thread handles one 16B chunk: row = tid>>2, chunk = tid&3.
    // swizzle: LDS slot (tid&3) receives global chunk (tid&3)^((srow>>1)&3).
    const int srow  = tid >> 2;
    const int sgcol = ((tid & 3) ^ ((srow >> 1) & 3)) * 8;
    const int lofs  = srow * 32 + (tid & 3) * 8;

    size_t aoffs[PA], boffs[PB];
#pragma unroll
    for (int p = 0; p < PA; ++p) aoffs[p] = (size_t)(tm + p * 64 + srow) * lda + sgcol;
#pragma unroll
    for (int p = 0; p < PB; ++p) boffs[p] = (size_t)(tn + p * 64 + srow) * ldb + sgcol;

    f32x4 acc[MI][NI];
#pragma unroll
    for (int i = 0; i < MI; ++i)
#pragma unroll
        for (int j = 0; j < NI; ++j) {
            f32x4 z = {0.0f, 0.0f, 0.0f, 0.0f};
            acc[i][j] = z;
        }

    const int wm   = (wave / WCN) * WTM;
    const int wn   = (wave % WCN) * WTN;
    const int l16  = lane & 15;
    const int quad = lane >> 4;
    // read-side swizzle: chunk = quad ^ ((row>>1)&3); row base multiple of 16
    const int rchunk = (quad ^ ((l16 >> 1) & 3)) * 8;
    const int arow0  = (wm + l16) * 32 + rchunk;
    const int brow0  = (wn + l16) * 32 + rchunk;

    for (int k0 = 0; k0 < K; k0 += 32) {
#pragma unroll
        for (int p = 0; p < PA; ++p)
            gload16(Ahi + aoffs[p] + k0, &As[0][p * 64 * 32 + lofs]);
#pragma unroll
        for (int p = 0; p < PB; ++p)
            gload16(Bhi + boffs[p] + k0, &Bs[0][p * 64 * 32 + lofs]);
        if constexpr (SPLIT) {
#pragma unroll
            for (int p = 0; p < PA; ++p)
                gload16(Alo + aoffs[p] + k0, &As[1][p * 64 * 32 + lofs]);
#pragma unroll
            for (int p = 0; p < PB; ++p)
                gload16(Blo + boffs[p] + k0, &Bs[1][p * 64 * 32 + lofs]);
        }
        __syncthreads();   // drains vmcnt -> LDS valid

        short8 ah[MI], bh[NI];
#pragma unroll
        for (int i = 0; i < MI; ++i) ah[i] = *(const short8*)&As[0][arow0 + i * 512];
#pragma unroll
        for (int j = 0; j < NI; ++j) bh[j] = *(const short8*)&Bs[0][brow0 + j * 512];
        if constexpr (SPLIT) {
            short8 al[MI], bl[NI];
#pragma unroll
            for (int i = 0; i < MI; ++i) al[i] = *(const short8*)&As[1][arow0 + i * 512];
#pragma unroll
            for (int j = 0; j < NI; ++j) bl[j] = *(const short8*)&Bs[1][brow0 + j * 512];
#pragma unroll
            for (int mi = 0; mi < MI; ++mi)
#pragma unroll
                for (int ni = 0; ni < NI; ++ni) {
                    acc[mi][ni] = MFMA16(ah[mi], bh[ni], acc[mi][ni]);
                    acc[mi][ni] = MFMA16(ah[mi], bl[ni], acc[mi][ni]);
                    acc[mi][ni] = MFMA16(al[mi], bh[ni], acc[mi][ni]);
                }
        } else {
#pragma unroll
            for (int mi = 0; mi < MI; ++mi)
#pragma unroll
                for (int ni = 0; ni < NI; ++ni)
                    acc[mi][ni] = MFMA16(ah[mi], bh[ni], acc[mi][ni]);
        }
        __syncthreads();   // before next-iter staging overwrites LDS
    }

    // C/D layout: col = lane&15, row = (lane>>4)*4 + reg  [verified m89/m91]
    const int rbase = tm + wm + quad * 4;
    const int cbase = tn + wn + l16;

    if constexpr (EPI == 0) {
#pragma unroll
        for (int mi = 0; mi < MI; ++mi)
#pragma unroll
            for (int ni = 0; ni < NI; ++ni) {
                f32x4 v = acc[mi][ni];
                const int col = cbase + ni * 16;
#pragma unroll
                for (int r = 0; r < 4; ++r)
                    obf_hi[(size_t)(rbase + mi * 16 + r) * ldc + col] = f2bf(v[r]);
            }
    } else if constexpr (EPI == 1) {
#pragma unroll
        for (int mi = 0; mi < MI; ++mi)
#pragma unroll
            for (int ni = 0; ni < NI; ++ni) {
                f32x4 v = acc[mi][ni];
                const int col = cbase + ni * 16;
                const float b = bias[col];
#pragma unroll
                for (int r = 0; r < 4; ++r) {
                    float g = gelu_f(v[r] + b);
                    __hip_bfloat16 h = f2bf(g);
                    size_t idx = (size_t)(rbase + mi * 16 + r) * ldc + col;
                    obf_hi[idx] = h;
                    obf_lo[idx] = f2bf(g - bf2f(h));
                }
            }
    } else if constexpr (EPI == 2) {
        const float SCL = 0.03608439182435161f;   // 1/sqrt(768)
#pragma unroll
        for (int mi = 0; mi < MI; ++mi) {
            float sE[4] = {0.f, 0.f, 0.f, 0.f};
            float sT[4] = {0.f, 0.f, 0.f, 0.f};
#pragma unroll
            for (int ni = 0; ni < NI; ++ni) {
                f32x4 v = acc[mi][ni];
                const int col = cbase + ni * 16;
                const float g = Gv[col];
#pragma unroll
                for (int r = 0; r < 4; ++r) {
                    float we = __expf(v[r] * SCL);
                    float w  = we * g;
                    obf_hi[(size_t)(rbase + mi * 16 + r) * ldc + col] = f2bf(w);
                    sE[r] += we;
                    sT[r] += w;
                }
            }
#pragma unroll
            for (int st = 1; st < 16; st <<= 1)
#pragma unroll
                for (int r = 0; r < 4; ++r) {
                    sE[r] += __shfl_xor(sE[r], st);
                    sT[r] += __shfl_xor(sT[r], st);
                }
            if (l16 == 0) {
#pragma unroll
                for (int r = 0; r < 4; ++r) {
                    atomicAdd(&Esum[rbase + mi * 16 + r], sE[r]);
                    atomicAdd(&Tsum[rbase + mi * 16 + r], sT[r]);
                }
            }
        }
    } else {  // EPI == 3: fp32 accumulate
#pragma unroll
        for (int mi = 0; mi < MI; ++mi)
#pragma unroll
            for (int ni = 0; ni < NI; ++ni) {
                f32x4 v = acc[mi][ni];
                const int col = cbase + ni * 16;
#pragma unroll
                for (int r = 0; r < 4; ++r) {
                    size_t idx = (size_t)(rbase + mi * 16 + r) * ldc + col;
                    ofp[idx] += v[r];
                }
            }
    }
}

// ---------------------------------------------------------------------------
// transpose f32 (RxC) -> bf16 (CxR), optional lo residual output
// ---------------------------------------------------------------------------
__global__ __launch_bounds__(256)
void transpose_f2b(const float* __restrict__ in, int ldin,
                   __hip_bfloat16* __restrict__ ohi, __hip_bfloat16* __restrict__ olo, int ldout)
{
    __shared__ float t[32][33];
    const int tx = threadIdx.x & 31;
    const int ty = threadIdx.x >> 5;
    const int r0 = blockIdx.y * 32;
    const int c0 = blockIdx.x * 32;
#pragma unroll
    for (int j = 0; j < 32; j += 8)
        t[ty + j][tx] = in[(size_t)(r0 + ty + j) * ldin + c0 + tx];
    __syncthreads();
#pragma unroll
    for (int j = 0; j < 32; j += 8) {
        float x = t[tx][ty + j];
        __hip_bfloat16 h = f2bf(x);
        size_t o = (size_t)(c0 + ty + j) * ldout + r0 + tx;
        ohi[o] = h;
        if (olo) olo[o] = f2bf(x - bf2f(h));
    }
}

__global__ __launch_bounds__(256)
void transpose_b2b(const __hip_bfloat16* __restrict__ in, int ldin,
                   __hip_bfloat16* __restrict__ out, int ldout)
{
    __shared__ __hip_bfloat16 t[32][33];
    const int tx = threadIdx.x & 31;
    const int ty = threadIdx.x >> 5;
    const int r0 = blockIdx.y * 32;
    const int c0 = blockIdx.x * 32;
#pragma unroll
    for (int j = 0; j < 32; j += 8)
        t[ty + j][tx] = in[(size_t)(r0 + ty + j) * ldin + c0 + tx];
    __syncthreads();
#pragma unroll
    for (int j = 0; j < 32; j += 8)
        out[(size_t)(c0 + ty + j) * ldout + r0 + tx] = t[tx][ty + j];
}

__global__ __launch_bounds__(256)
void cvt_split(const float* __restrict__ in, __hip_bfloat16* __restrict__ hi,
               __hip_bfloat16* __restrict__ lo)
{
    const int i = (blockIdx.x * 256 + threadIdx.x) * 4;
    f32x4 v = *(const f32x4*)(in + i);
#pragma unroll
    for (int k = 0; k < 4; ++k) {
        __hip_bfloat16 h = f2bf(v[k]);
        hi[i + k] = h;
        lo[i + k] = f2bf(v[k] - bf2f(h));
    }
}

// ---------------------------------------------------------------------------
// head tail: r = H2 @ Wh + bh (fp32, hi+lo input), NIG transforms, optional G.
// ---------------------------------------------------------------------------
__global__ __launch_bounds__(256)
void head_tail(const __hip_bfloat16* __restrict__ H2hi, const __hip_bfloat16* __restrict__ H2lo,
               const float* __restrict__ Wh, const float* __restrict__ bh,
               const float* __restrict__ gamp,
               float* __restrict__ outBase, float* __restrict__ Gout)
{
    __shared__ float sa[64], sb[64];
    const int tid = threadIdx.x;
    const int rl  = tid >> 2;
    const int c   = tid & 3;
    const int row = blockIdx.x * 64 + rl;
    const __hip_bfloat16* hh = H2hi + (size_t)row * DH2;
    const __hip_bfloat16* hl = H2lo + (size_t)row * DH2;
    float acc = bh[c];
    for (int k = 0; k < DH2; ++k) {
        float h = bf2f(hh[k]) + bf2f(hl[k]);
        acc = fmaf(h, Wh[k * 4 + c], acc);
    }
    float sp = softplus_f(acc);
    if (c == 0) {
        outBase[row] = acc;                        // mu
    } else if (c == 1) {
        outBase[NT + row] = sp + 1e-6f;            // v
    } else if (c == 2) {
        float a0 = (sp + 1.0f) + 1e-6f;            // match ref assoc order
        outBase[2 * NT + row] = a0;
        if (Gout) sa[rl] = a0 - 1.0f;              // match ref's a0-1 rounding
    } else {
        float b0 = sp + 1e-6f;
        outBase[3 * NT + row] = b0;
        if (Gout) sb[rl] = b0;
    }
    if (Gout != nullptr) {
        __syncthreads();
        if (c == 0) {
            float u   = sb[rl] / fmaxf(sa[rl], 1e-8f);
            float sig = 1.0f / (1.0f + expf(-u));  // fp32 cliff identical to ref
            Gout[row] = 1.0f - gamp[0] * sig;
        }
    }
}

// ---------------------------------------------------------------------------
// Y = X + gelu(alpha*Macc + bg); alpha = G/(E*max(G*T/E,1e-8))
// ---------------------------------------------------------------------------
__global__ __launch_bounds__(256)
void fuse_y(const float* __restrict__ X, const float* __restrict__ Macc,
            const float* __restrict__ G, const float* __restrict__ E,
            const float* __restrict__ T, const float* __restrict__ bg,
            __hip_bfloat16* __restrict__ Yhi, __hip_bfloat16* __restrict__ Ylo)
{
    const int i   = blockIdx.x * 256 + threadIdx.x;
    const int row = i / DD;
    const int col = i - row * DD;
    const float g = G[row], e = E[row], t = T[row];
    const float denom = fmaxf(g * t / e, 1e-8f);
    const float alpha = g / (e * denom);
    const float m = alpha * Macc[i];
    const float y = X[i] + gelu_f(m + bg[col]);
    __hip_bfloat16 h = f2bf(y);
    Yhi[i] = h;
    Ylo[i] = f2bf(y - bf2f(h));
}

// ---------------------------------------------------------------------------
extern "C" void kernel_launch(void* const* d_in, const int* in_sizes, int n_in,
                              void* d_out, int out_size, void* d_ws, size_t ws_size,
                              hipStream_t stream)
{
    (void)in_sizes; (void)n_in; (void)out_size; (void)ws_size;
    const float* X   = (const float*)d_in[0];
    const float* Wq  = (const float*)d_in[1];
    const float* Wk  = (const float*)d_in[2];
    const float* Wg  = (const float*)d_in[3];
    const float* bg  = (const float*)d_in[4];
    const float* gam = (const float*)d_in[5];
    const float* iW1 = (const float*)d_in[6];
    const float* ib1 = (const float*)d_in[7];
    const float* iW2 = (const float*)d_in[8];
    const float* ib2 = (const float*)d_in[9];
    const float* iWh = (const float*)d_in[10];
    const float* ibh = (const float*)d_in[11];
    const float* fW1 = (const float*)d_in[12];
    const float* fb1 = (const float*)d_in[13];
    const float* fW2 = (const float*)d_in[14];
    const float* fb2 = (const float*)d_in[15];
    const float* fWh = (const float*)d_in[16];
    const float* fbh = (const float*)d_in[17];
    float* out = (float*)d_out;

    char* cur = (char*)d_ws;
    auto alloc = [&](size_t bytes) -> char* {
        char* p = cur;
        cur += (bytes + 255) & ~(size_t)255;
        return p;
    };
    typedef __hip_bfloat16 bf;
    bf* Xhi    = (bf*)alloc((size_t)NT * DD * 2);
    bf* Xlo    = (bf*)alloc((size_t)NT * DD * 2);
    bf* WqkvT  = (bf*)alloc((size_t)3 * DD * DD * 2);    // 2304 x 768
    bf* iW1hiT = (bf*)alloc((size_t)DH1 * DD * 2);
    bf* iW1loT = (bf*)alloc((size_t)DH1 * DD * 2);
    bf* iW2hiT = (bf*)alloc((size_t)DH2 * DH1 * 2);
    bf* iW2loT = (bf*)alloc((size_t)DH2 * DH1 * 2);
    bf* fW1hiT = (bf*)alloc((size_t)DH1 * DD * 2);
    bf* fW1loT = (bf*)alloc((size_t)DH1 * DD * 2);
    bf* fW2hiT = (bf*)alloc((size_t)DH2 * DH1 * 2);
    bf* fW2loT = (bf*)alloc((size_t)DH2 * DH1 * 2);
    bf* QKV    = (bf*)alloc((size_t)NT * 3 * DD * 2);    // 8192 x 2304
    bf* VbT    = (bf*)alloc((size_t)DD * NT * 2);        // 768 x 8192
    bf* H1hi   = (bf*)alloc((size_t)NT * DH1 * 2);
    bf* H1lo   = (bf*)alloc((size_t)NT * DH1 * 2);
    bf* H2hi   = (bf*)alloc((size_t)NT * DH2 * 2);
    bf* H2lo   = (bf*)alloc((size_t)NT * DH2 * 2);
    float* G    = (float*)alloc((size_t)NT * 4);
    float* E    = (float*)alloc((size_t)NT * 4);
    float* T    = (float*)alloc((size_t)NT * 4);
    bf* Wp     = (bf*)alloc((size_t)NT * PANEL * 2);     // 8192 x 2048 panel
    float* Macc = (float*)alloc((size_t)NT * DD * 4);
    bf* Yhi    = (bf*)alloc((size_t)NT * DD * 2);
    bf* Ylo    = (bf*)alloc((size_t)NT * DD * 2);

    const dim3 blk(256);

    // 1. converts / transposes
    cvt_split<<<dim3(NT * DD / 1024), blk, 0, stream>>>(X, Xhi, Xlo);
    transpose_f2b<<<dim3(DD / 32, DD / 32), blk, 0, stream>>>(Wq, DD, WqkvT, nullptr, DD);
    transpose_f2b<<<dim3(DD / 32, DD / 32), blk, 0, stream>>>(Wk, DD, WqkvT + (size_t)DD * DD, nullptr, DD);
    transpose_f2b<<<dim3(DD / 32, DD / 32), blk, 0, stream>>>(Wg, DD, WqkvT + (size_t)2 * DD * DD, nullptr, DD);
    transpose_f2b<<<dim3(DH1 / 32, DD / 32), blk, 0, stream>>>(iW1, DH1, iW1hiT, iW1loT, DD);
    transpose_f2b<<<dim3(DH2 / 32, DH1 / 32), blk, 0, stream>>>(iW2, DH2, iW2hiT, iW2loT, DH1);
    transpose_f2b<<<dim3(DH1 / 32, DD / 32), blk, 0, stream>>>(fW1, DH1, fW1hiT, fW1loT, DD);
    transpose_f2b<<<dim3(DH2 / 32, DH1 / 32), blk, 0, stream>>>(fW2, DH2, fW2hiT, fW2loT, DH1);

    // 2. head 1 (split-bf16 for G-cliff safety)
    gemm_bt<1, true, 128, 64><<<dim3(DH1 / 64, NT / 128), blk, 0, stream>>>(
        Xhi, Xlo, DD, iW1hiT, iW1loT, DD, H1hi, H1lo, nullptr, DH1, ib1, nullptr, nullptr, nullptr, DD);
    gemm_bt<1, true, 64, 64><<<dim3(DH2 / 64, NT / 64), blk, 0, stream>>>(
        H1hi, H1lo, DH1, iW2hiT, iW2loT, DH1, H2hi, H2lo, nullptr, DH2, ib2, nullptr, nullptr, nullptr, DH1);
    head_tail<<<dim3(NT / 64), blk, 0, stream>>>(H2hi, H2lo, iWh, ibh, gam, out, G);

    // 3. QKV projection
    gemm_bt<0, false, 128, 128><<<dim3(3 * DD / 128, NT / 128), blk, 0, stream>>>(
        Xhi, nullptr, DD, WqkvT, nullptr, DD, QKV, nullptr, nullptr, 3 * DD,
        nullptr, nullptr, nullptr, nullptr, DD);
    transpose_b2b<<<dim3(DD / 32, NT / 32), blk, 0, stream>>>(QKV + 2 * DD, 3 * DD, VbT, NT);

    hipMemsetAsync(E, 0, (size_t)NT * 4, stream);
    hipMemsetAsync(T, 0, (size_t)NT * 4, stream);
    hipMemsetAsync(Macc, 0, (size_t)NT * DD * 4, stream);

    // 4. attention panels (2048 cols each)
    for (int p = 0; p < NPAN; ++p) {
        const bf* Kp = QKV + (size_t)p * PANEL * (3 * DD) + DD;
        gemm_bt<2, false, 128, 128><<<dim3(PANEL / 128, NT / 128), blk, 0, stream>>>(
            QKV, nullptr, 3 * DD, Kp, nullptr, 3 * DD, Wp, nullptr, nullptr, PANEL,
            nullptr, G + p * PANEL, E, T, DD);
        gemm_bt<3, false, 128, 64><<<dim3(DD / 64, NT / 128), blk, 0, stream>>>(
            Wp, nullptr, PANEL, VbT + p * PANEL, nullptr, NT, nullptr, nullptr, Macc, DD,
            nullptr, nullptr, nullptr, nullptr, PANEL);
    }

    // 5. Y = X + gelu(alpha*Macc + bg)
    fuse_y<<<dim3(NT * DD / 256), blk, 0, stream>>>(X, Macc, G, E, T, bg, Yhi, Ylo);

    // 6. head 2
    gemm_bt<1, true, 128, 64><<<dim3(DH1 / 64, NT / 128), blk, 0, stream>>>(
        Yhi, Ylo, DD, fW1hiT, fW1loT, DD, H1hi, H1lo, nullptr, DH1, fb1, nullptr, nullptr, nullptr, DD);
    gemm_bt<1, true, 64, 64><<<dim3(DH2 / 64, NT / 64), blk, 0, stream>>>(
        H1hi, H1lo, DH1, fW2hiT, fW2loT, DH1, H2hi, H2lo, nullptr, DH2, fb2, nullptr, nullptr, nullptr, DH1);
    head_tail<<<dim3(NT / 64), blk, 0, stream>>>(H2hi, H2lo, fWh, fbh, gam, out + 4 * NT, nullptr);
}

// Round 3
// 720.884 us; speedup vs baseline: 1.3690x; 1.0952x over previous
//
#include <hip/hip_runtime.h>
#include <hip/hip_bf16.h>
#include <math.h>
#include <stdint.h>
#include <stddef.h>

// ---------------------------------------------------------------------------
// MetaEvidentialGSL: N=8192, D=768, H1=512, H2=256
//  1. split X into bf16 hi/lo; transpose+convert weights to bf16
//  2. head1 via split-bf16 MFMA GEMMs -> m0,v0,a0,b0 + gate G
//  3. QKV = X @ [Wq|Wk|Wg] (one bf16 GEMM); V transposed
//  4. attention in 2 panels of 4096: Wp = exp(QK^T/sqrt(D))*G_j (bf16) with
//     row-sum atomics E/T; Macc += Wp @ V (fp32)
//  5. Y = X + gelu(alpha*Macc + bg), alpha = G/(E*max(G*T/E,1e-8))
//  6. head2 on Y -> mu,v,al,be
// R2: swizzle killed bank conflicts (3.5M -> 0).
// R3: BK=64 (half the barriers, 2x compute per barrier), PANEL=4096 with
//     Wp aliased over dead Xhi/Xlo/H1/H2 buffers, heads on 64x64 tiles.
// ---------------------------------------------------------------------------

#define NT    8192
#define DD    768
#define DH1   512
#define DH2   256
#define PANEL 4096
#define NPAN  (NT / PANEL)

typedef __attribute__((ext_vector_type(8))) short  short8;
typedef __attribute__((ext_vector_type(4))) float  f32x4;

#define MFMA16(a, b, c) __builtin_amdgcn_mfma_f32_16x16x32_bf16((a), (b), (c), 0, 0, 0)

__device__ __forceinline__ float bf2f(__hip_bfloat16 x) { return __bfloat162float(x); }
__device__ __forceinline__ __hip_bfloat16 f2bf(float x) { return __float2bfloat16(x); }

__device__ __forceinline__ float gelu_f(float x) {
    return 0.5f * x * (1.0f + erff(x * 0.7071067811865476f));
}
__device__ __forceinline__ float softplus_f(float x) {
    return (x > 20.0f) ? x : log1pf(expf(x));
}

// async 16B/lane global->LDS. LDS dest must be wave-uniform base + lane*16.
__device__ __forceinline__ void gload16(const __hip_bfloat16* g, __hip_bfloat16* l) {
    __builtin_amdgcn_global_load_lds(
        (const __attribute__((address_space(1))) void*)(const void*)g,
        (__attribute__((address_space(3))) void*)(void*)l,
        16, 0, 0);
}

// ---------------------------------------------------------------------------
// GEMM: C(MxN) = A(MxK) @ Bt(NxK)^T. Tile TM x TN, BK=64, 4 waves, 256 thr.
// LDS: row-major 64-elem rows (128 B = 8 chunks of 16 B). Chunk c of row r
// stored at slot c ^ (r&7): any 8-lane read group covers all 8 bank-groups
// (conflict-free; rows 8-15 alias as the free 2-way). Staging applies the
// XOR to the global source column so global_load_lds dest stays tid*16.
// SPLIT: A,B given as hi+lo bf16 pairs; computes hi*hi + hi*lo + lo*hi.
// EPI: 0 = store bf16; 1 = bias+gelu -> split bf16 (hi/lo)
//      2 = w=exp(acc/sqrt(D))*G[col] -> bf16, atomic rowsum E (exp) / T (w)
//      3 = fp32 accumulate (ofp[idx] += acc)
// ---------------------------------------------------------------------------
template <int EPI, bool SPLIT, int TM, int TN>
__global__ __launch_bounds__(256)
void gemm_bt(const __hip_bfloat16* __restrict__ Ahi, const __hip_bfloat16* __restrict__ Alo, int lda,
             const __hip_bfloat16* __restrict__ Bhi, const __hip_bfloat16* __restrict__ Blo, int ldb,
             __hip_bfloat16* __restrict__ obf_hi, __hip_bfloat16* __restrict__ obf_lo,
             float* __restrict__ ofp, int ldc,
             const float* __restrict__ bias, const float* __restrict__ Gv,
             float* __restrict__ Esum, float* __restrict__ Tsum, int K)
{
    constexpr int NB  = SPLIT ? 2 : 1;
    constexpr int WRM = (TM == 128 && TN == 128) ? 2 : (TM == 128 ? 4 : 2);
    constexpr int WCN = 4 / WRM;
    constexpr int WTM = TM / WRM;
    constexpr int WTN = TN / WCN;
    constexpr int MI  = WTM / 16;
    constexpr int NI  = WTN / 16;
    constexpr int PA  = TM / 32;    // staging passes (32 rows x 128 B = 4 KB each)
    constexpr int PB  = TN / 32;

    __shared__ __align__(16) __hip_bfloat16 As[NB][TM * 64];
    __shared__ __align__(16) __hip_bfloat16 Bs[NB][TN * 64];

    const int tid  = threadIdx.x;
    const int wave = tid >> 6;
    const int lane = tid & 63;
    const int tm = blockIdx.y * TM;
    const int tn = blockIdx.x * TN;

    // staging: thread stages one 16B chunk: row = tid>>3, slot = tid&7.
    // slot (tid&7) receives global chunk (tid&7)^(row&7).
    const int srow  = tid >> 3;
    const int sgcol = ((tid & 7) ^ (srow & 7)) * 8;
    const int lofs  = tid * 8;     // elems within a 2048-elem pass region

    size_t aoffs[PA], boffs[PB];
#pragma unroll
    for (int p = 0; p < PA; ++p) aoffs[p] = (size_t)(tm + p * 32 + srow) * lda + sgcol;
#pragma unroll
    for (int p = 0; p < PB; ++p) boffs[p] = (size_t)(tn + p * 32 + srow) * ldb + sgcol;

    f32x4 acc[MI][NI];
#pragma unroll
    for (int i = 0; i < MI; ++i)
#pragma unroll
        for (int j = 0; j < NI; ++j) {
            f32x4 z = {0.0f, 0.0f, 0.0f, 0.0f};
            acc[i][j] = z;
        }

    const int wm   = (wave / WCN) * WTM;
    const int wn   = (wave % WCN) * WTN;
    const int l16  = lane & 15;
    const int quad = lane >> 4;
    const int rsw  = l16 & 7;      // read-side swizzle key (row&7 == l16&7)

    for (int k0 = 0; k0 < K; k0 += 64) {
#pragma unroll
        for (int p = 0; p < PA; ++p)
            gload16(Ahi + aoffs[p] + k0, &As[0][p * 2048 + lofs]);
#pragma unroll
        for (int p = 0; p < PB; ++p)
            gload16(Bhi + boffs[p] + k0, &Bs[0][p * 2048 + lofs]);
        if constexpr (SPLIT) {
#pragma unroll
            for (int p = 0; p < PA; ++p)
                gload16(Alo + aoffs[p] + k0, &As[1][p * 2048 + lofs]);
#pragma unroll
            for (int p = 0; p < PB; ++p)
                gload16(Blo + boffs[p] + k0, &Bs[1][p * 2048 + lofs]);
        }
        __syncthreads();   // drains vmcnt -> LDS valid

#pragma unroll
        for (int kh = 0; kh < 2; ++kh) {
            const int aslot = ((kh * 4 + quad) ^ rsw) * 8;
            short8 ah[MI], bh[NI];
#pragma unroll
            for (int i = 0; i < MI; ++i)
                ah[i] = *(const short8*)&As[0][(wm + i * 16 + l16) * 64 + aslot];
#pragma unroll
            for (int j = 0; j < NI; ++j)
                bh[j] = *(const short8*)&Bs[0][(wn + j * 16 + l16) * 64 + aslot];
            if constexpr (SPLIT) {
                short8 al[MI], bl[NI];
#pragma unroll
                for (int i = 0; i < MI; ++i)
                    al[i] = *(const short8*)&As[1][(wm + i * 16 + l16) * 64 + aslot];
#pragma unroll
                for (int j = 0; j < NI; ++j)
                    bl[j] = *(const short8*)&Bs[1][(wn + j * 16 + l16) * 64 + aslot];
#pragma unroll
                for (int mi = 0; mi < MI; ++mi)
#pragma unroll
                    for (int ni = 0; ni < NI; ++ni) {
                        acc[mi][ni] = MFMA16(ah[mi], bh[ni], acc[mi][ni]);
                        acc[mi][ni] = MFMA16(ah[mi], bl[ni], acc[mi][ni]);
                        acc[mi][ni] = MFMA16(al[mi], bh[ni], acc[mi][ni]);
                    }
            } else {
#pragma unroll
                for (int mi = 0; mi < MI; ++mi)
#pragma unroll
                    for (int ni = 0; ni < NI; ++ni)
                        acc[mi][ni] = MFMA16(ah[mi], bh[ni], acc[mi][ni]);
            }
        }
        __syncthreads();   // before next-iter staging overwrites LDS
    }

    // C/D layout: col = lane&15, row = (lane>>4)*4 + reg  [verified m89/m91]
    const int rbase = tm + wm + quad * 4;
    const int cbase = tn + wn + l16;

    if constexpr (EPI == 0) {
#pragma unroll
        for (int mi = 0; mi < MI; ++mi)
#pragma unroll
            for (int ni = 0; ni < NI; ++ni) {
                f32x4 v = acc[mi][ni];
                const int col = cbase + ni * 16;
#pragma unroll
                for (int r = 0; r < 4; ++r)
                    obf_hi[(size_t)(rbase + mi * 16 + r) * ldc + col] = f2bf(v[r]);
            }
    } else if constexpr (EPI == 1) {
#pragma unroll
        for (int mi = 0; mi < MI; ++mi)
#pragma unroll
            for (int ni = 0; ni < NI; ++ni) {
                f32x4 v = acc[mi][ni];
                const int col = cbase + ni * 16;
                const float b = bias[col];
#pragma unroll
                for (int r = 0; r < 4; ++r) {
                    float g = gelu_f(v[r] + b);
                    __hip_bfloat16 h = f2bf(g);
                    size_t idx = (size_t)(rbase + mi * 16 + r) * ldc + col;
                    obf_hi[idx] = h;
                    obf_lo[idx] = f2bf(g - bf2f(h));
                }
            }
    } else if constexpr (EPI == 2) {
        const float SCL = 0.03608439182435161f;   // 1/sqrt(768)
#pragma unroll
        for (int mi = 0; mi < MI; ++mi) {
            float sE[4] = {0.f, 0.f, 0.f, 0.f};
            float sT[4] = {0.f, 0.f, 0.f, 0.f};
#pragma unroll
            for (int ni = 0; ni < NI; ++ni) {
                f32x4 v = acc[mi][ni];
                const int col = cbase + ni * 16;
                const float g = Gv[col];
#pragma unroll
                for (int r = 0; r < 4; ++r) {
                    float we = __expf(v[r] * SCL);
                    float w  = we * g;
                    obf_hi[(size_t)(rbase + mi * 16 + r) * ldc + col] = f2bf(w);
                    sE[r] += we;
                    sT[r] += w;
                }
            }
#pragma unroll
            for (int st = 1; st < 16; st <<= 1)
#pragma unroll
                for (int r = 0; r < 4; ++r) {
                    sE[r] += __shfl_xor(sE[r], st);
                    sT[r] += __shfl_xor(sT[r], st);
                }
            if (l16 == 0) {
#pragma unroll
                for (int r = 0; r < 4; ++r) {
                    atomicAdd(&Esum[rbase + mi * 16 + r], sE[r]);
                    atomicAdd(&Tsum[rbase + mi * 16 + r], sT[r]);
                }
            }
        }
    } else {  // EPI == 3: fp32 accumulate
#pragma unroll
        for (int mi = 0; mi < MI; ++mi)
#pragma unroll
            for (int ni = 0; ni < NI; ++ni) {
                f32x4 v = acc[mi][ni];
                const int col = cbase + ni * 16;
#pragma unroll
                for (int r = 0; r < 4; ++r) {
                    size_t idx = (size_t)(rbase + mi * 16 + r) * ldc + col;
                    ofp[idx] += v[r];
                }
            }
    }
}

// ---------------------------------------------------------------------------
// transpose f32 (RxC) -> bf16 (CxR), optional lo residual output
// ---------------------------------------------------------------------------
__global__ __launch_bounds__(256)
void transpose_f2b(const float* __restrict__ in, int ldin,
                   __hip_bfloat16* __restrict__ ohi, __hip_bfloat16* __restrict__ olo, int ldout)
{
    __shared__ float t[32][33];
    const int tx = threadIdx.x & 31;
    const int ty = threadIdx.x >> 5;
    const int r0 = blockIdx.y * 32;
    const int c0 = blockIdx.x * 32;
#pragma unroll
    for (int j = 0; j < 32; j += 8)
        t[ty + j][tx] = in[(size_t)(r0 + ty + j) * ldin + c0 + tx];
    __syncthreads();
#pragma unroll
    for (int j = 0; j < 32; j += 8) {
        float x = t[tx][ty + j];
        __hip_bfloat16 h = f2bf(x);
        size_t o = (size_t)(c0 + ty + j) * ldout + r0 + tx;
        ohi[o] = h;
        if (olo) olo[o] = f2bf(x - bf2f(h));
    }
}

__global__ __launch_bounds__(256)
void transpose_b2b(const __hip_bfloat16* __restrict__ in, int ldin,
                   __hip_bfloat16* __restrict__ out, int ldout)
{
    __shared__ __hip_bfloat16 t[32][33];
    const int tx = threadIdx.x & 31;
    const int ty = threadIdx.x >> 5;
    const int r0 = blockIdx.y * 32;
    const int c0 = blockIdx.x * 32;
#pragma unroll
    for (int j = 0; j < 32; j += 8)
        t[ty + j][tx] = in[(size_t)(r0 + ty + j) * ldin + c0 + tx];
    __syncthreads();
#pragma unroll
    for (int j = 0; j < 32; j += 8)
        out[(size_t)(c0 + ty + j) * ldout + r0 + tx] = t[tx][ty + j];
}

__global__ __launch_bounds__(256)
void cvt_split(const float* __restrict__ in, __hip_bfloat16* __restrict__ hi,
               __hip_bfloat16* __restrict__ lo)
{
    const int i = (blockIdx.x * 256 + threadIdx.x) * 4;
    f32x4 v = *(const f32x4*)(in + i);
#pragma unroll
    for (int k = 0; k < 4; ++k) {
        __hip_bfloat16 h = f2bf(v[k]);
        hi[i + k] = h;
        lo[i + k] = f2bf(v[k] - bf2f(h));
    }
}

// ---------------------------------------------------------------------------
// head tail: r = H2 @ Wh + bh (fp32, hi+lo input), NIG transforms, optional G.
// ---------------------------------------------------------------------------
__global__ __launch_bounds__(256)
void head_tail(const __hip_bfloat16* __restrict__ H2hi, const __hip_bfloat16* __restrict__ H2lo,
               const float* __restrict__ Wh, const float* __restrict__ bh,
               const float* __restrict__ gamp,
               float* __restrict__ outBase, float* __restrict__ Gout)
{
    __shared__ float sa[64], sb[64];
    const int tid = threadIdx.x;
    const int rl  = tid >> 2;
    const int c   = tid & 3;
    const int row = blockIdx.x * 64 + rl;
    const __hip_bfloat16* hh = H2hi + (size_t)row * DH2;
    const __hip_bfloat16* hl = H2lo + (size_t)row * DH2;
    float acc = bh[c];
    for (int k = 0; k < DH2; ++k) {
        float h = bf2f(hh[k]) + bf2f(hl[k]);
        acc = fmaf(h, Wh[k * 4 + c], acc);
    }
    float sp = softplus_f(acc);
    if (c == 0) {
        outBase[row] = acc;                        // mu
    } else if (c == 1) {
        outBase[NT + row] = sp + 1e-6f;            // v
    } else if (c == 2) {
        float a0 = (sp + 1.0f) + 1e-6f;            // match ref assoc order
        outBase[2 * NT + row] = a0;
        if (Gout) sa[rl] = a0 - 1.0f;              // match ref's a0-1 rounding
    } else {
        float b0 = sp + 1e-6f;
        outBase[3 * NT + row] = b0;
        if (Gout) sb[rl] = b0;
    }
    if (Gout != nullptr) {
        __syncthreads();
        if (c == 0) {
            float u   = sb[rl] / fmaxf(sa[rl], 1e-8f);
            float sig = 1.0f / (1.0f + expf(-u));  // fp32 cliff identical to ref
            Gout[row] = 1.0f - gamp[0] * sig;
        }
    }
}

// ---------------------------------------------------------------------------
// Y = X + gelu(alpha*Macc + bg); alpha = G/(E*max(G*T/E,1e-8))
// ---------------------------------------------------------------------------
__global__ __launch_bounds__(256)
void fuse_y(const float* __restrict__ X, const float* __restrict__ Macc,
            const float* __restrict__ G, const float* __restrict__ E,
            const float* __restrict__ T, const float* __restrict__ bg,
            __hip_bfloat16* __restrict__ Yhi, __hip_bfloat16* __restrict__ Ylo)
{
    const int i   = blockIdx.x * 256 + threadIdx.x;
    const int row = i / DD;
    const int col = i - row * DD;
    const float g = G[row], e = E[row], t = T[row];
    const float denom = fmaxf(g * t / e, 1e-8f);
    const float alpha = g / (e * denom);
    const float m = alpha * Macc[i];
    const float y = X[i] + gelu_f(m + bg[col]);
    __hip_bfloat16 h = f2bf(y);
    Yhi[i] = h;
    Ylo[i] = f2bf(y - bf2f(h));
}

// ---------------------------------------------------------------------------
extern "C" void kernel_launch(void* const* d_in, const int* in_sizes, int n_in,
                              void* d_out, int out_size, void* d_ws, size_t ws_size,
                              hipStream_t stream)
{
    (void)in_sizes; (void)n_in; (void)out_size; (void)ws_size;
    const float* X   = (const float*)d_in[0];
    const float* Wq  = (const float*)d_in[1];
    const float* Wk  = (const float*)d_in[2];
    const float* Wg  = (const float*)d_in[3];
    const float* bg  = (const float*)d_in[4];
    const float* gam = (const float*)d_in[5];
    const float* iW1 = (const float*)d_in[6];
    const float* ib1 = (const float*)d_in[7];
    const float* iW2 = (const float*)d_in[8];
    const float* ib2 = (const float*)d_in[9];
    const float* iWh = (const float*)d_in[10];
    const float* ibh = (const float*)d_in[11];
    const float* fW1 = (const float*)d_in[12];
    const float* fb1 = (const float*)d_in[13];
    const float* fW2 = (const float*)d_in[14];
    const float* fb2 = (const float*)d_in[15];
    const float* fWh = (const float*)d_in[16];
    const float* fbh = (const float*)d_in[17];
    float* out = (float*)d_out;

    char* cur = (char*)d_ws;
    auto alloc = [&](size_t bytes) -> char* {
        char* p = cur;
        cur += (bytes + 255) & ~(size_t)255;
        return p;
    };
    typedef __hip_bfloat16 bf;

    // Region A (67.1 MB): Wp panel, aliased over buffers that are dead during
    // the attention phase (Xhi/Xlo/H1*/H2* — verified lifetimes in comments
    // at each launch below).
    char* regA = alloc((size_t)NT * PANEL * 2);
    bf* Wp   = (bf*)regA;
    bf* Xhi  = (bf*)(regA);
    bf* Xlo  = (bf*)(regA + (size_t)NT * DD * 2);
    bf* H1hi = (bf*)(regA + (size_t)NT * DD * 4);
    bf* H1lo = (bf*)(regA + (size_t)NT * DD * 4 + (size_t)NT * DH1 * 2);
    bf* H2hi = (bf*)(regA + (size_t)NT * DD * 4 + (size_t)NT * DH1 * 4);
    bf* H2lo = (bf*)(regA + (size_t)NT * DD * 4 + (size_t)NT * DH1 * 4 + (size_t)NT * DH2 * 2);

    bf* WqkvT  = (bf*)alloc((size_t)3 * DD * DD * 2);    // 2304 x 768
    bf* iW1hiT = (bf*)alloc((size_t)DH1 * DD * 2);
    bf* iW1loT = (bf*)alloc((size_t)DH1 * DD * 2);
    bf* iW2hiT = (bf*)alloc((size_t)DH2 * DH1 * 2);
    bf* iW2loT = (bf*)alloc((size_t)DH2 * DH1 * 2);
    bf* fW1hiT = (bf*)alloc((size_t)DH1 * DD * 2);
    bf* fW1loT = (bf*)alloc((size_t)DH1 * DD * 2);
    bf* fW2hiT = (bf*)alloc((size_t)DH2 * DH1 * 2);
    bf* fW2loT = (bf*)alloc((size_t)DH2 * DH1 * 2);
    bf* QKV    = (bf*)alloc((size_t)NT * 3 * DD * 2);    // 8192 x 2304
    bf* VbT    = (bf*)alloc((size_t)DD * NT * 2);        // 768 x 8192
    float* G    = (float*)alloc((size_t)NT * 4);
    float* E    = (float*)alloc((size_t)NT * 4);
    float* T    = (float*)alloc((size_t)NT * 4);
    float* Macc = (float*)alloc((size_t)NT * DD * 4);
    bf* Yhi    = (bf*)alloc((size_t)NT * DD * 2);
    bf* Ylo    = (bf*)alloc((size_t)NT * DD * 2);

    const dim3 blk(256);

    // 1. converts / transposes
    cvt_split<<<dim3(NT * DD / 1024), blk, 0, stream>>>(X, Xhi, Xlo);
    transpose_f2b<<<dim3(DD / 32, DD / 32), blk, 0, stream>>>(Wq, DD, WqkvT, nullptr, DD);
    transpose_f2b<<<dim3(DD / 32, DD / 32), blk, 0, stream>>>(Wk, DD, WqkvT + (size_t)DD * DD, nullptr, DD);
    transpose_f2b<<<dim3(DD / 32, DD / 32), blk, 0, stream>>>(Wg, DD, WqkvT + (size_t)2 * DD * DD, nullptr, DD);
    transpose_f2b<<<dim3(DH1 / 32, DD / 32), blk, 0, stream>>>(iW1, DH1, iW1hiT, iW1loT, DD);
    transpose_f2b<<<dim3(DH2 / 32, DH1 / 32), blk, 0, stream>>>(iW2, DH2, iW2hiT, iW2loT, DH1);
    transpose_f2b<<<dim3(DH1 / 32, DD / 32), blk, 0, stream>>>(fW1, DH1, fW1hiT, fW1loT, DD);
    transpose_f2b<<<dim3(DH2 / 32, DH1 / 32), blk, 0, stream>>>(fW2, DH2, fW2hiT, fW2loT, DH1);

    // 2. head 1 (split-bf16 for G-cliff safety). Xlo dead after W1 GEMM.
    gemm_bt<1, true, 64, 64><<<dim3(DH1 / 64, NT / 64), blk, 0, stream>>>(
        Xhi, Xlo, DD, iW1hiT, iW1loT, DD, H1hi, H1lo, nullptr, DH1, ib1, nullptr, nullptr, nullptr, DD);
    gemm_bt<1, true, 64, 64><<<dim3(DH2 / 64, NT / 64), blk, 0, stream>>>(
        H1hi, H1lo, DH1, iW2hiT, iW2loT, DH1, H2hi, H2lo, nullptr, DH2, ib2, nullptr, nullptr, nullptr, DH1);
    head_tail<<<dim3(NT / 64), blk, 0, stream>>>(H2hi, H2lo, iWh, ibh, gam, out, G);

    // 3. QKV projection (last reader of Xhi)
    gemm_bt<0, false, 128, 128><<<dim3(3 * DD / 128, NT / 128), blk, 0, stream>>>(
        Xhi, nullptr, DD, WqkvT, nullptr, DD, QKV, nullptr, nullptr, 3 * DD,
        nullptr, nullptr, nullptr, nullptr, DD);
    transpose_b2b<<<dim3(DD / 32, NT / 32), blk, 0, stream>>>(QKV + 2 * DD, 3 * DD, VbT, NT);

    hipMemsetAsync(E, 0, (size_t)NT * 4, stream);
    hipMemsetAsync(T, 0, (size_t)NT * 4, stream);
    hipMemsetAsync(Macc, 0, (size_t)NT * DD * 4, stream);

    // 4. attention panels (4096 cols each). Wp write clobbers region A —
    //    Xhi/Xlo/H1*/H2* are all dead here.
    for (int p = 0; p < NPAN; ++p) {
        const bf* Kp = QKV + (size_t)p * PANEL * (3 * DD) + DD;
        gemm_bt<2, false, 128, 128><<<dim3(PANEL / 128, NT / 128), blk, 0, stream>>>(
            QKV, nullptr, 3 * DD, Kp, nullptr, 3 * DD, Wp, nullptr, nullptr, PANEL,
            nullptr, G + p * PANEL, E, T, DD);
        gemm_bt<3, false, 128, 64><<<dim3(DD / 64, NT / 128), blk, 0, stream>>>(
            Wp, nullptr, PANEL, VbT + p * PANEL, nullptr, NT, nullptr, nullptr, Macc, DD,
            nullptr, nullptr, nullptr, nullptr, PANEL);
    }

    // 5. Y = X + gelu(alpha*Macc + bg). Wp dead after this point.
    fuse_y<<<dim3(NT * DD / 256), blk, 0, stream>>>(X, Macc, G, E, T, bg, Yhi, Ylo);

    // 6. head 2 (re-uses H1*/H2* slots inside region A — Wp is dead)
    gemm_bt<1, true, 64, 64><<<dim3(DH1 / 64, NT / 64), blk, 0, stream>>>(
        Yhi, Ylo, DD, fW1hiT, fW1loT, DD, H1hi, H1lo, nullptr, DH1, fb1, nullptr, nullptr, nullptr, DD);
    gemm_bt<1, true, 64, 64><<<dim3(DH2 / 64, NT / 64), blk, 0, stream>>>(
        H1hi, H1lo, DH1, fW2hiT, fW2loT, DH1, H2hi, H2lo, nullptr, DH2, fb2, nullptr, nullptr, nullptr, DH1);
    head_tail<<<dim3(NT / 64), blk, 0, stream>>>(H2hi, H2lo, fWh, fbh, gam, out + 4 * NT, nullptr);
}